// Round 2
// baseline (67.729 us; speedup 1.0000x reference)
//
#include <hip/hip_runtime.h>

// DCN cross, B=8192, D=256, L=4, fp32.
// Algebraic reformulation: with d_l = x0.W_l, c_j = b_lin_j + bias_j,
// P_l = sum_{j<l} c_j, e_l = P_l.W_l:
//   s_l = t_l*d_l + e_l,  t_{l+1} = t_l + s_l,  t_0 = 1
//   out = x0*(1 + sum_l s_l) + P_L
// All 7 reductions (d0..d3, e1..e3) are independent -> one interleaved
// 6-step __shfl_xor phase (depth 6) instead of 4 serialized reductions.
// One 64-lane wave per row; lane owns 4 contiguous floats (float4).

__global__ __launch_bounds__(256) void cross_kernel(
    const float* __restrict__ x,
    const float* __restrict__ W,
    const float* __restrict__ b_lin,
    const float* __restrict__ bias,
    float* __restrict__ out,
    int B)
{
    const int wave = threadIdx.x >> 6;
    const int lane = threadIdx.x & 63;
    const int row  = blockIdx.x * 4 + wave;
    if (row >= B) return;

    const float4 x0 = ((const float4*)(x + (size_t)row * 256))[lane];

    // W rows (broadcast across waves, L1/L2-resident)
    float4 w0 = ((const float4*)(W + 0 * 256))[lane];
    float4 w1 = ((const float4*)(W + 1 * 256))[lane];
    float4 w2 = ((const float4*)(W + 2 * 256))[lane];
    float4 w3 = ((const float4*)(W + 3 * 256))[lane];

    // c_j = b_lin_j + bias_j (lane slice); prefix sums P_l
    const float bl0 = b_lin[0], bl1 = b_lin[1], bl2 = b_lin[2], bl3 = b_lin[3];
    float4 c0 = ((const float4*)(bias + 0 * 256))[lane];
    float4 c1 = ((const float4*)(bias + 1 * 256))[lane];
    float4 c2 = ((const float4*)(bias + 2 * 256))[lane];
    float4 c3 = ((const float4*)(bias + 3 * 256))[lane];
    c0.x += bl0; c0.y += bl0; c0.z += bl0; c0.w += bl0;
    c1.x += bl1; c1.y += bl1; c1.z += bl1; c1.w += bl1;
    c2.x += bl2; c2.y += bl2; c2.z += bl2; c2.w += bl2;
    c3.x += bl3; c3.y += bl3; c3.z += bl3; c3.w += bl3;

    float4 P1 = c0;
    float4 P2 = {P1.x + c1.x, P1.y + c1.y, P1.z + c1.z, P1.w + c1.w};
    float4 P3 = {P2.x + c2.x, P2.y + c2.y, P2.z + c2.z, P2.w + c2.w};
    float4 PL = {P3.x + c3.x, P3.y + c3.y, P3.z + c3.z, P3.w + c3.w};

    // 7 independent lane-partials
    float v[7];
    v[0] = x0.x * w0.x + x0.y * w0.y + x0.z * w0.z + x0.w * w0.w;  // d0
    v[1] = x0.x * w1.x + x0.y * w1.y + x0.z * w1.z + x0.w * w1.w;  // d1
    v[2] = x0.x * w2.x + x0.y * w2.y + x0.z * w2.z + x0.w * w2.w;  // d2
    v[3] = x0.x * w3.x + x0.y * w3.y + x0.z * w3.z + x0.w * w3.w;  // d3
    v[4] = P1.x * w1.x + P1.y * w1.y + P1.z * w1.z + P1.w * w1.w;  // e1
    v[5] = P2.x * w2.x + P2.y * w2.y + P2.z * w2.z + P2.w * w2.w;  // e2
    v[6] = P3.x * w3.x + P3.y * w3.y + P3.z * w3.z + P3.w * w3.w;  // e3

    // one interleaved reduction phase: depth 6, width 7
    #pragma unroll
    for (int off = 32; off > 0; off >>= 1) {
        #pragma unroll
        for (int k = 0; k < 7; ++k)
            v[k] += __shfl_xor(v[k], off, 64);
    }

    // uniform scalar recurrence
    const float d0 = v[0], d1 = v[1], d2 = v[2], d3 = v[3];
    const float e1 = v[4], e2 = v[5], e3 = v[6];
    float t = 1.0f;
    float s0 = t * d0;            t += s0;
    float s1 = fmaf(t, d1, e1);   t += s1;
    float s2 = fmaf(t, d2, e2);   t += s2;
    float s3 = fmaf(t, d3, e3);   t += s3;   // t = 1 + sum s_l

    float4 o;
    o.x = fmaf(x0.x, t, PL.x);
    o.y = fmaf(x0.y, t, PL.y);
    o.z = fmaf(x0.z, t, PL.z);
    o.w = fmaf(x0.w, t, PL.w);
    ((float4*)(out + (size_t)row * 256))[lane] = o;
}

extern "C" void kernel_launch(void* const* d_in, const int* in_sizes, int n_in,
                              void* d_out, int out_size, void* d_ws, size_t ws_size,
                              hipStream_t stream) {
    const float* x     = (const float*)d_in[0];
    const float* W     = (const float*)d_in[1];
    const float* b_lin = (const float*)d_in[2];
    const float* bias  = (const float*)d_in[3];
    float* out = (float*)d_out;

    const int L = in_sizes[2];          // 4 (kernel assumes 4)
    const int D = in_sizes[1] / L;      // 256 (kernel assumes 256)
    const int B = in_sizes[0] / D;      // 8192

    const int grid = (B + 3) / 4;       // 4 rows per 256-thread block
    cross_kernel<<<grid, 256, 0, stream>>>(x, W, b_lin, bias, out, B);
}